// Round 5
// baseline (1249.594 us; speedup 1.0000x reference)
//
#include <hip/hip_runtime.h>

#define LBL 32
#define NPIX (736 * 736)   // 541696
#define NB 529             // blocks per batch (1 float4-quad per thread)
#define BATCH 8
#define DELTA_AGG 0.5f
#define DELTA_DIS 1.5f
#define REG_W 0.001f

// ws layout (floats):
//  partA: [PA_BASE, +8*529*160)  per (batch,block): cnt[32] ([0]=saw-label-0), sum[32*4]
//  red:   [RED_BASE, +8*192)     per batch: cnt_k[32], mean[32*4]
//  partC: [PC_BASE, +8*529*64)   per (batch,block): val[32], cnt[32]
//  cnt:   [CNT_BASE, +16)        int completion counters (memset to 0 each call)
#define PA_BASE 0
#define RED_BASE (BATCH * NB * 160)           // 677120
#define PC_BASE (RED_BASE + BATCH * 192)      // 678656
#define CNT_BASE (PC_BASE + BATCH * NB * 64)  // 949504

// ===== Kernel 1: pass A streaming + last-block-per-batch reduction ==========
__global__ __launch_bounds__(256) void kAB(
    const float* __restrict__ emb, const int* __restrict__ inst,
    const float* __restrict__ kern, const float* __restrict__ mask,
    float* __restrict__ ws, int* __restrict__ counters) {
  const int b = blockIdx.y;
  const int t = threadIdx.x;
  __shared__ float s_cnt[LBL];   // [0] is the "saw label 0" flag
  __shared__ float s_sum[LBL * 4];
  if (t < LBL) s_cnt[t] = 0.f;
  if (t < LBL * 4) s_sum[t] = 0.f;
  __syncthreads();

  const long base = (long)b * NPIX;
  const int q = blockIdx.x * 256 + t;  // one quad per thread
  const int4 iv = ((const int4*)(inst + base))[q];
  const float4 kv = ((const float4*)(kern + base))[q];
  const float4 mv = ((const float4*)(mask + base))[q];
  const float* eb = emb + (long)b * 4 * NPIX;
  const float4 e0 = ((const float4*)(eb))[q];
  const float4 e1 = ((const float4*)(eb + NPIX))[q];
  const float4 e2 = ((const float4*)(eb + 2 * NPIX))[q];
  const float4 e3 = ((const float4*)(eb + 3 * NPIX))[q];

  const int labs[4] = {iv.x, iv.y, iv.z, iv.w};
  const float ks[4] = {kv.x, kv.y, kv.z, kv.w};
  const float ms[4] = {mv.x, mv.y, mv.z, mv.w};
  const float c0[4] = {e0.x, e0.y, e0.z, e0.w};
  const float c1[4] = {e1.x, e1.y, e1.z, e1.w};
  const float c2[4] = {e2.x, e2.y, e2.z, e2.w};
  const float c3[4] = {e3.x, e3.y, e3.z, e3.w};

  bool has0 = false;
#pragma unroll
  for (int j = 0; j < 4; j++) {
    const int lk = (ms[j] > 0.5f && ks[j] > 0.5f) ? labs[j] : 0;
    if (lk > 0) {
      atomicAdd(&s_cnt[lk], 1.0f);
      atomicAdd(&s_sum[lk * 4 + 0], c0[j]);
      atomicAdd(&s_sum[lk * 4 + 1], c1[j]);
      atomicAdd(&s_sum[lk * 4 + 2], c2[j]);
      atomicAdd(&s_sum[lk * 4 + 3], c3[j]);
    } else {
      has0 = true;
    }
  }
  if (has0) s_cnt[0] = 1.0f;  // benign race: all writers store 1
  __syncthreads();

  float* po = ws + PA_BASE + (size_t)(b * NB + blockIdx.x) * 160;
  if (t < 160) po[t] = (t < 32) ? s_cnt[t] : s_sum[t - 32];

  // ---- completion counter: last block of this batch reduces ----
  __threadfence();   // release: make partial stores device-visible
  __syncthreads();
  __shared__ int s_last;
  if (t == 0) s_last = (atomicAdd(&counters[b], 1) == NB - 1);
  __syncthreads();
  if (!s_last) return;
  __threadfence();   // acquire: see all other blocks' partials

  const float* pa = ws + PA_BASE + (size_t)b * NB * 160;
  // sums: 128 elems x 2 group-chunks (265 iters/thread)
  float s = 0.f;
  {
    const int cs = t >> 7, es = t & 127;
    const float* p = pa + 32 + es;
    for (int g = cs; g < NB; g += 2) s += p[(size_t)g * 160];
  }
  // cnts: 32 elems x 8 group-chunks (67 iters/thread)
  float sc = 0.f;
  {
    const int cc = t >> 5, ec = t & 31;
    const float* p = pa + ec;
    for (int g = cc; g < NB; g += 8) sc += p[(size_t)g * 160];
  }
  __shared__ float redS[256], redC[256], ctot[LBL];
  redS[t] = s;
  redC[t] = sc;
  __syncthreads();
  float* rd = ws + RED_BASE + b * 192;
  if (t < LBL) {
    float c8 = 0.f;
#pragma unroll
    for (int k = 0; k < 8; k++) c8 += redC[k * 32 + t];
    ctot[t] = c8;
    rd[t] = c8;  // cnt_k ([0] = presence-flag sum)
  }
  __syncthreads();
  if (t < 128) {
    const int l = t >> 2;
    const float stot = redS[t] + redS[128 + t];
    rd[32 + t] = (l == 0) ? 0.f : stot / fmaxf(ctot[l], 1.0f);  // mean
  }
}

// ===== Kernel 2: pass C streaming + last-block reduction + finalize =========
__global__ __launch_bounds__(256) void kCD(
    const float* __restrict__ emb, const int* __restrict__ inst,
    const float* __restrict__ mask, float* __restrict__ ws,
    int* __restrict__ counters, float* __restrict__ out) {
  const int b = blockIdx.y;
  const int t = threadIdx.x;
  __shared__ float s_mean[LBL * 4];
  __shared__ float s_val[LBL];
  __shared__ float s_cta[LBL];
  const float* rd = ws + RED_BASE + b * 192;
  if (t < LBL * 4) s_mean[t] = rd[32 + t];
  if (t < LBL) {
    s_val[t] = 0.f;
    s_cta[t] = 0.f;
  }
  __syncthreads();

  const long base = (long)b * NPIX;
  const int q = blockIdx.x * 256 + t;
  const int4 iv = ((const int4*)(inst + base))[q];
  const float4 mv = ((const float4*)(mask + base))[q];
  const float* eb = emb + (long)b * 4 * NPIX;
  const float4 e0 = ((const float4*)(eb))[q];
  const float4 e1 = ((const float4*)(eb + NPIX))[q];
  const float4 e2 = ((const float4*)(eb + 2 * NPIX))[q];
  const float4 e3 = ((const float4*)(eb + 3 * NPIX))[q];

  const int labs[4] = {iv.x, iv.y, iv.z, iv.w};
  const float ms[4] = {mv.x, mv.y, mv.z, mv.w};
  const float c0[4] = {e0.x, e0.y, e0.z, e0.w};
  const float c1[4] = {e1.x, e1.y, e1.z, e1.w};
  const float c2[4] = {e2.x, e2.y, e2.z, e2.w};
  const float c3[4] = {e3.x, e3.y, e3.z, e3.w};

#pragma unroll
  for (int j = 0; j < 4; j++) {
    const int li = (ms[j] > 0.5f) ? labs[j] : 0;
    if (li > 0) {  // label 0 excluded from l_agg (nz mask)
      const float d0 = c0[j] - s_mean[li * 4 + 0];
      const float d1 = c1[j] - s_mean[li * 4 + 1];
      const float d2 = c2[j] - s_mean[li * 4 + 2];
      const float d3 = c3[j] - s_mean[li * 4 + 3];
      const float sq = d0 * d0 + d1 * d1 + d2 * d2 + d3 * d3;
      const float dist = (sq > 0.f) ? sqrtf(sq) : 0.f;
      const float tt = fmaxf(dist - DELTA_AGG, 0.f);
      atomicAdd(&s_val[li], logf(fmaf(tt, tt, 1.0f)));
      atomicAdd(&s_cta[li], 1.0f);
    }
  }
  __syncthreads();
  float* po = ws + PC_BASE + (size_t)(b * NB + blockIdx.x) * 64;
  if (t < 64) po[t] = (t < 32) ? s_val[t] : s_cta[t - 32];

  // ---- completion counter: last block of this batch finalizes ----
  __threadfence();
  __syncthreads();
  __shared__ int s_last;
  if (t == 0) s_last = (atomicAdd(&counters[8 + b], 1) == NB - 1);
  __syncthreads();
  if (!s_last) return;
  __threadfence();

  // reduce 529 x 64 partials
  const float* pc = ws + PC_BASE + (size_t)b * NB * 64;
  const int c4 = t >> 6, e4 = t & 63;
  float s = 0.f;
  for (int g = c4; g < NB; g += 4) s += pc[(size_t)g * 64 + e4];
  __shared__ float red4[256];
  red4[t] = s;
  __shared__ float scc[LBL];
  if (t >= 128 && t < 160) scc[t - 128] = rd[t - 128];  // cnt_k
  __syncthreads();
  __shared__ float sv[64];  // [0,32)=sum_v, [32,64)=cnt_a
  if (t < 64) sv[t] = red4[t] + red4[64 + t] + red4[128 + t] + red4[192 + t];
  __syncthreads();

  if (t < 64) {  // wave 0 only
    const int lane = t;
    const bool pres = (lane < LBL) && (scc[lane & 31] > 0.f);
    const unsigned long long bal_p = __ballot(pres);
    const int num_instance = __popcll(bal_p);
    const bool nz = pres && (lane > 0);
    const unsigned long long bal_nz = __ballot(nz);

    float agg = 0.f;
    if (nz) agg = sv[lane] / fmaxf(sv[32 + lane], 1.0f);

    float reg = 0.f;
    if (pres) {
      float sq = 0.f;
#pragma unroll
      for (int d = 0; d < 4; d++) sq += s_mean[lane * 4 + d] * s_mean[lane * 4 + d];
      const float nrm = (sq > 0.f) ? sqrtf(sq) : 0.f;
      reg = logf(nrm + 1.0f);
    }

    float dis = 0.f, npair = 0.f;
    for (int pi = lane; pi < LBL * LBL; pi += 64) {
      const int i = pi >> 5, j = pi & 31;
      if (i != j && ((bal_nz >> i) & 1ull) && ((bal_nz >> j) & 1ull)) {
        float sq = 0.f;
#pragma unroll
        for (int d = 0; d < 4; d++) {
          const float df = s_mean[i * 4 + d] - s_mean[j * 4 + d];
          sq += df * df;
        }
        const float pdist = (sq > 0.f) ? sqrtf(sq) : 0.f;
        const float tt = fmaxf(2.0f * DELTA_DIS - pdist, 0.f);
        dis += logf(fmaf(tt, tt, 1.0f));
        npair += 1.0f;
      }
    }

#pragma unroll
    for (int o = 32; o > 0; o >>= 1) {
      agg += __shfl_down(agg, o);
      reg += __shfl_down(reg, o);
      dis += __shfl_down(dis, o);
      npair += __shfl_down(npair, o);
    }

    if (lane == 0) {
      const float l_agg = agg / fmaxf((float)(num_instance - 1), 1.0f);
      const float l_dis = (num_instance > 2) ? dis / fmaxf(npair, 1.0f) : 0.f;
      const float l_reg = reg / fmaxf((float)num_instance, 1.0f) * REG_W;
      const float loss = l_agg + l_dis + l_reg;
      out[b] = (num_instance <= 1) ? 0.f : loss;
    }
  }
}

extern "C" void kernel_launch(void* const* d_in, const int* in_sizes, int n_in,
                              void* d_out, int out_size, void* d_ws,
                              size_t ws_size, hipStream_t stream) {
  const float* emb = (const float*)d_in[0];
  const int* instance = (const int*)d_in[1];
  const float* kern = (const float*)d_in[2];
  const float* mask = (const float*)d_in[3];
  float* out = (float*)d_out;
  float* ws = (float*)d_ws;
  int* counters = (int*)((char*)d_ws + (size_t)CNT_BASE * sizeof(float));

  // Zero only the 16 completion counters (ws is re-poisoned each call).
  hipMemsetAsync(counters, 0, 16 * sizeof(int), stream);

  dim3 grid(NB, BATCH);  // 4232 blocks, one float4-quad per thread
  kAB<<<grid, 256, 0, stream>>>(emb, instance, kern, mask, ws, counters);
  kCD<<<grid, 256, 0, stream>>>(emb, instance, mask, ws, counters, out);
}

// Round 6
// 207.263 us; speedup vs baseline: 6.0290x; 6.0290x over previous
//
#include <hip/hip_runtime.h>

#define LBL 32
#define NPIX (736 * 736)   // 541696
#define NQ (NPIX / 4)      // 135424 float4-quads per batch
#define BATCH 8
#define G 128              // blocks per batch
#define CHUNK (NQ / G)     // 1058 contiguous quads per block (exact: 128*1058=135424)
#define FULL_IT 4          // 4 full 256-thread iterations ...
#define TAIL 34            // ... + 34-thread tail (4*256+34 = 1058)
#define DELTA_AGG 0.5f
#define DELTA_DIS 1.5f
#define REG_W 0.001f

// ws layout (floats), ~0.9 MB total (all slots plain-stored before read — no memset):
//  partA: [PA_BASE, +8*128*160)  per (batch,block): cnt[32] ([0]=saw-label-0), sum[32*4]
//  red:   [RED_BASE, +8*192)     per batch: cnt_k[32], mean[32*4]
//  partC: [PC_BASE, +8*128*64)   per (batch,block): val[32], cnt[32]
#define PA_BASE 0
#define RED_BASE (BATCH * G * 160)        // 163840
#define PC_BASE (RED_BASE + BATCH * 192)  // 165376

// ===== Pass A: kernel-region count + emb sums (contiguous chunks, pipelined)
__global__ __launch_bounds__(256) void kA(
    const float* __restrict__ emb, const int* __restrict__ inst,
    const float* __restrict__ kern, const float* __restrict__ mask,
    float* __restrict__ ws) {
  const int b = blockIdx.y;
  const int t = threadIdx.x;
  __shared__ float s_cnt[LBL];   // [0] is the "saw label 0" flag
  __shared__ float s_sum[LBL * 4];
  if (t < LBL) s_cnt[t] = 0.f;
  if (t < LBL * 4) s_sum[t] = 0.f;
  __syncthreads();

  const long base = (long)b * NPIX;
  const float* eb = emb + (long)b * 4 * NPIX;
  const int4* ip = (const int4*)(inst + base);
  const float4* kp = (const float4*)(kern + base);
  const float4* mp = (const float4*)(mask + base);
  const float4* p0 = (const float4*)(eb);
  const float4* p1 = (const float4*)(eb + NPIX);
  const float4* p2 = (const float4*)(eb + 2 * NPIX);
  const float4* p3 = (const float4*)(eb + 3 * NPIX);

  const int start = blockIdx.x * CHUNK;
  bool has0 = false;

  // pipeline stage registers (current)
  int q = start + t;
  int4 iv = ip[q];
  float4 kv = kp[q], mv = mp[q];
  float4 e0 = p0[q], e1 = p1[q], e2 = p2[q], e3 = p3[q];
  bool cur_v = true;

  for (int it = 0; it < FULL_IT; ++it) {
    // prefetch next iteration (issues before current's atomic phase)
    const int qn = start + (it + 1) * 256 + t;
    const bool nv = (it < FULL_IT - 1) || (t < TAIL);
    int4 niv;
    float4 nkv, nmv, ne0, ne1, ne2, ne3;
    if (nv) {
      niv = ip[qn]; nkv = kp[qn]; nmv = mp[qn];
      ne0 = p0[qn]; ne1 = p1[qn]; ne2 = p2[qn]; ne3 = p3[qn];
    }
    // process current (always fully valid inside this loop)
    {
      const int labs[4] = {iv.x, iv.y, iv.z, iv.w};
      const float ks[4] = {kv.x, kv.y, kv.z, kv.w};
      const float ms[4] = {mv.x, mv.y, mv.z, mv.w};
      const float c0[4] = {e0.x, e0.y, e0.z, e0.w};
      const float c1[4] = {e1.x, e1.y, e1.z, e1.w};
      const float c2[4] = {e2.x, e2.y, e2.z, e2.w};
      const float c3[4] = {e3.x, e3.y, e3.z, e3.w};
#pragma unroll
      for (int j = 0; j < 4; j++) {
        const int lk = (ms[j] > 0.5f && ks[j] > 0.5f) ? labs[j] : 0;
        if (lk > 0) {
          atomicAdd(&s_cnt[lk], 1.0f);
          atomicAdd(&s_sum[lk * 4 + 0], c0[j]);
          atomicAdd(&s_sum[lk * 4 + 1], c1[j]);
          atomicAdd(&s_sum[lk * 4 + 2], c2[j]);
          atomicAdd(&s_sum[lk * 4 + 3], c3[j]);
        } else {
          has0 = true;
        }
      }
    }
    iv = niv; kv = nkv; mv = nmv;
    e0 = ne0; e1 = ne1; e2 = ne2; e3 = ne3;
    cur_v = nv;
  }
  // tail (threads 0..TAIL-1)
  if (cur_v) {
    const int labs[4] = {iv.x, iv.y, iv.z, iv.w};
    const float ks[4] = {kv.x, kv.y, kv.z, kv.w};
    const float ms[4] = {mv.x, mv.y, mv.z, mv.w};
    const float c0[4] = {e0.x, e0.y, e0.z, e0.w};
    const float c1[4] = {e1.x, e1.y, e1.z, e1.w};
    const float c2[4] = {e2.x, e2.y, e2.z, e2.w};
    const float c3[4] = {e3.x, e3.y, e3.z, e3.w};
#pragma unroll
    for (int j = 0; j < 4; j++) {
      const int lk = (ms[j] > 0.5f && ks[j] > 0.5f) ? labs[j] : 0;
      if (lk > 0) {
        atomicAdd(&s_cnt[lk], 1.0f);
        atomicAdd(&s_sum[lk * 4 + 0], c0[j]);
        atomicAdd(&s_sum[lk * 4 + 1], c1[j]);
        atomicAdd(&s_sum[lk * 4 + 2], c2[j]);
        atomicAdd(&s_sum[lk * 4 + 3], c3[j]);
      } else {
        has0 = true;
      }
    }
  }

  if (has0) s_cnt[0] = 1.0f;  // benign race: all writers store 1
  __syncthreads();
  float* po = ws + PA_BASE + (size_t)(b * G + blockIdx.x) * 160;
  if (t < 160) po[t] = (t < 32) ? s_cnt[t] : s_sum[t - 32];
}

// ===== Reduce A partials -> cnt_k + means (one block per batch) =============
__global__ __launch_bounds__(256) void kB(float* __restrict__ ws) {
  const int b = blockIdx.x, t = threadIdx.x;
  const float* pa = ws + PA_BASE + (size_t)b * G * 160;
  // sums: 128 elems x 2 group-chunks
  float s = 0.f;
  {
    const int cs = t >> 7, es = t & 127;
    const float* p = pa + 32 + es;
    for (int g = cs; g < G; g += 2) s += p[(size_t)g * 160];
  }
  // cnts: 32 elems x 8 group-chunks
  float sc = 0.f;
  {
    const int cc = t >> 5, ec = t & 31;
    const float* p = pa + ec;
    for (int g = cc; g < G; g += 8) sc += p[(size_t)g * 160];
  }
  __shared__ float redS[256], redC[256], ctot[LBL];
  redS[t] = s;
  redC[t] = sc;
  __syncthreads();
  float* rd = ws + RED_BASE + b * 192;
  if (t < LBL) {
    float c8 = 0.f;
#pragma unroll
    for (int k = 0; k < 8; k++) c8 += redC[k * 32 + t];
    ctot[t] = c8;
    rd[t] = c8;  // cnt_k ([0] = presence-flag sum)
  }
  __syncthreads();
  if (t < 128) {
    const int l = t >> 2;
    const float stot = redS[t] + redS[128 + t];
    rd[32 + t] = (l == 0) ? 0.f : stot / fmaxf(ctot[l], 1.0f);  // mean
  }
}

// ===== Pass C: aggregation loss segment sums (same streaming structure) =====
__global__ __launch_bounds__(256) void kC(
    const float* __restrict__ emb, const int* __restrict__ inst,
    const float* __restrict__ mask, float* __restrict__ ws) {
  const int b = blockIdx.y;
  const int t = threadIdx.x;
  __shared__ float s_mean[LBL * 4];
  __shared__ float s_val[LBL];
  __shared__ float s_cta[LBL];
  const float* rd = ws + RED_BASE + b * 192;
  if (t < LBL * 4) s_mean[t] = rd[32 + t];
  if (t < LBL) {
    s_val[t] = 0.f;
    s_cta[t] = 0.f;
  }
  __syncthreads();

  const long base = (long)b * NPIX;
  const float* eb = emb + (long)b * 4 * NPIX;
  const int4* ip = (const int4*)(inst + base);
  const float4* mp = (const float4*)(mask + base);
  const float4* p0 = (const float4*)(eb);
  const float4* p1 = (const float4*)(eb + NPIX);
  const float4* p2 = (const float4*)(eb + 2 * NPIX);
  const float4* p3 = (const float4*)(eb + 3 * NPIX);

  const int start = blockIdx.x * CHUNK;
  int q = start + t;
  int4 iv = ip[q];
  float4 mv = mp[q];
  float4 e0 = p0[q], e1 = p1[q], e2 = p2[q], e3 = p3[q];
  bool cur_v = true;

  for (int it = 0; it < FULL_IT; ++it) {
    const int qn = start + (it + 1) * 256 + t;
    const bool nv = (it < FULL_IT - 1) || (t < TAIL);
    int4 niv;
    float4 nmv, ne0, ne1, ne2, ne3;
    if (nv) {
      niv = ip[qn]; nmv = mp[qn];
      ne0 = p0[qn]; ne1 = p1[qn]; ne2 = p2[qn]; ne3 = p3[qn];
    }
    {
      const int labs[4] = {iv.x, iv.y, iv.z, iv.w};
      const float ms[4] = {mv.x, mv.y, mv.z, mv.w};
      const float c0[4] = {e0.x, e0.y, e0.z, e0.w};
      const float c1[4] = {e1.x, e1.y, e1.z, e1.w};
      const float c2[4] = {e2.x, e2.y, e2.z, e2.w};
      const float c3[4] = {e3.x, e3.y, e3.z, e3.w};
#pragma unroll
      for (int j = 0; j < 4; j++) {
        const int li = (ms[j] > 0.5f) ? labs[j] : 0;
        if (li > 0) {
          const float d0 = c0[j] - s_mean[li * 4 + 0];
          const float d1 = c1[j] - s_mean[li * 4 + 1];
          const float d2 = c2[j] - s_mean[li * 4 + 2];
          const float d3 = c3[j] - s_mean[li * 4 + 3];
          const float sq = d0 * d0 + d1 * d1 + d2 * d2 + d3 * d3;
          const float dist = (sq > 0.f) ? sqrtf(sq) : 0.f;
          const float tt = fmaxf(dist - DELTA_AGG, 0.f);
          atomicAdd(&s_val[li], logf(fmaf(tt, tt, 1.0f)));
          atomicAdd(&s_cta[li], 1.0f);
        }
      }
    }
    iv = niv; mv = nmv;
    e0 = ne0; e1 = ne1; e2 = ne2; e3 = ne3;
    cur_v = nv;
  }
  if (cur_v) {
    const int labs[4] = {iv.x, iv.y, iv.z, iv.w};
    const float ms[4] = {mv.x, mv.y, mv.z, mv.w};
    const float c0[4] = {e0.x, e0.y, e0.z, e0.w};
    const float c1[4] = {e1.x, e1.y, e1.z, e1.w};
    const float c2[4] = {e2.x, e2.y, e2.z, e2.w};
    const float c3[4] = {e3.x, e3.y, e3.z, e3.w};
#pragma unroll
    for (int j = 0; j < 4; j++) {
      const int li = (ms[j] > 0.5f) ? labs[j] : 0;
      if (li > 0) {
        const float d0 = c0[j] - s_mean[li * 4 + 0];
        const float d1 = c1[j] - s_mean[li * 4 + 1];
        const float d2 = c2[j] - s_mean[li * 4 + 2];
        const float d3 = c3[j] - s_mean[li * 4 + 3];
        const float sq = d0 * d0 + d1 * d1 + d2 * d2 + d3 * d3;
        const float dist = (sq > 0.f) ? sqrtf(sq) : 0.f;
        const float tt = fmaxf(dist - DELTA_AGG, 0.f);
        atomicAdd(&s_val[li], logf(fmaf(tt, tt, 1.0f)));
        atomicAdd(&s_cta[li], 1.0f);
      }
    }
  }
  __syncthreads();
  float* po = ws + PC_BASE + (size_t)(b * G + blockIdx.x) * 64;
  if (t < 64) po[t] = (t < 32) ? s_val[t] : s_cta[t - 32];
}

// ===== Reduce C + finalize (one block per batch) ============================
__global__ __launch_bounds__(256) void kD(const float* __restrict__ ws,
                                          float* __restrict__ out) {
  const int b = blockIdx.x;
  const int t = threadIdx.x;
  const float* pc = ws + PC_BASE + (size_t)b * G * 64;
  const int c4 = t >> 6, e4 = t & 63;
  float s = 0.f;
  for (int g = c4; g < G; g += 4) s += pc[(size_t)g * 64 + e4];
  __shared__ float red4[256];
  red4[t] = s;
  const float* rd = ws + RED_BASE + b * 192;
  __shared__ float sm[LBL * 4];
  __shared__ float scc[LBL];
  if (t < 128) sm[t] = rd[32 + t];
  if (t >= 128 && t < 160) scc[t - 128] = rd[t - 128];
  __syncthreads();
  __shared__ float sv[64];  // [0,32)=sum_v, [32,64)=cnt_a
  if (t < 64) sv[t] = red4[t] + red4[64 + t] + red4[128 + t] + red4[192 + t];
  __syncthreads();

  if (t < 64) {  // wave 0 only
    const int lane = t;
    const bool pres = (lane < LBL) && (scc[lane & 31] > 0.f);
    const unsigned long long bal_p = __ballot(pres);
    const int num_instance = __popcll(bal_p);
    const bool nz = pres && (lane > 0);
    const unsigned long long bal_nz = __ballot(nz);

    float agg = 0.f;
    if (nz) agg = sv[lane] / fmaxf(sv[32 + lane], 1.0f);

    float reg = 0.f;
    if (pres) {
      float sq = 0.f;
#pragma unroll
      for (int d = 0; d < 4; d++) sq += sm[lane * 4 + d] * sm[lane * 4 + d];
      const float nrm = (sq > 0.f) ? sqrtf(sq) : 0.f;
      reg = logf(nrm + 1.0f);
    }

    float dis = 0.f, npair = 0.f;
    for (int pi = lane; pi < LBL * LBL; pi += 64) {
      const int i = pi >> 5, j = pi & 31;
      if (i != j && ((bal_nz >> i) & 1ull) && ((bal_nz >> j) & 1ull)) {
        float sq = 0.f;
#pragma unroll
        for (int d = 0; d < 4; d++) {
          const float df = sm[i * 4 + d] - sm[j * 4 + d];
          sq += df * df;
        }
        const float pdist = (sq > 0.f) ? sqrtf(sq) : 0.f;
        const float tt = fmaxf(2.0f * DELTA_DIS - pdist, 0.f);
        dis += logf(fmaf(tt, tt, 1.0f));
        npair += 1.0f;
      }
    }

#pragma unroll
    for (int o = 32; o > 0; o >>= 1) {
      agg += __shfl_down(agg, o);
      reg += __shfl_down(reg, o);
      dis += __shfl_down(dis, o);
      npair += __shfl_down(npair, o);
    }

    if (lane == 0) {
      const float l_agg = agg / fmaxf((float)(num_instance - 1), 1.0f);
      const float l_dis = (num_instance > 2) ? dis / fmaxf(npair, 1.0f) : 0.f;
      const float l_reg = reg / fmaxf((float)num_instance, 1.0f) * REG_W;
      const float loss = l_agg + l_dis + l_reg;
      out[b] = (num_instance <= 1) ? 0.f : loss;
    }
  }
}

extern "C" void kernel_launch(void* const* d_in, const int* in_sizes, int n_in,
                              void* d_out, int out_size, void* d_ws,
                              size_t ws_size, hipStream_t stream) {
  const float* emb = (const float*)d_in[0];
  const int* instance = (const int*)d_in[1];
  const float* kern = (const float*)d_in[2];
  const float* mask = (const float*)d_in[3];
  float* out = (float*)d_out;
  float* ws = (float*)d_ws;

  dim3 grid(G, BATCH);  // 1024 blocks, contiguous 1058-quad chunks
  kA<<<grid, 256, 0, stream>>>(emb, instance, kern, mask, ws);
  kB<<<BATCH, 256, 0, stream>>>(ws);
  kC<<<grid, 256, 0, stream>>>(emb, instance, mask, ws);
  kD<<<BATCH, 256, 0, stream>>>(ws, out);
}